// Round 8
// baseline (12858.670 us; speedup 1.0000x reference)
//
#include <hip/hip_runtime.h>
#include <hip/hip_bf16.h>

// BitNet-style ternary MLP: out = relu(x @ Wfc_q^T * s_fc)^2 @ Wproj_q^T * s_proj
// B=8 S=4096 D=2048 H=5120 -> M=32768.
// GEMMs: 256x256 tile, BK=32, 8 waves, 16x16x32 MFMA, TWO LDS buffers (64 KiB
// -> 2 blocks/CU, 4 waves/SIMD: inter-block async overlap is the lever this
// round). Per tile: stage T+1 into freed buffer, read cur, 32 MFMA,
// vmcnt(0)+barrier. T2 swizzle (4-chunk domain) via pre-swizzled global src;
// T5 setprio; T1 bijective XCD swizzle.

typedef __attribute__((ext_vector_type(8))) short short8;
typedef __attribute__((ext_vector_type(4))) float f32x4;

#define BM 256
#define BN 256
#define BK 32
#define BUFE 16384  // elems (shorts) per buffer: A[256][32] + B[256][32] = 32 KiB

__device__ __forceinline__ unsigned short f2bf(float f) {
  unsigned int u = __float_as_uint(f);
  u += 0x7FFFu + ((u >> 16) & 1u);  // RNE
  return (unsigned short)(u >> 16);
}

__device__ __forceinline__ void gload_lds16(const void* gsrc, void* ldst) {
  __builtin_amdgcn_global_load_lds(
      (const __attribute__((address_space(1))) unsigned int*)gsrc,
      (__attribute__((address_space(3))) unsigned int*)ldst, 16, 0, 0);
}

// ---------- pass 1: |w| sum partials (deterministic, fp64 accumulate) ----------
__global__ void k_reduce_abs(const float4* __restrict__ w, int n4,
                             double* __restrict__ partial) {
  __shared__ double sm[256];
  double s = 0.0;
  const int stride = gridDim.x * blockDim.x;
  for (int i = blockIdx.x * blockDim.x + threadIdx.x; i < n4; i += stride) {
    float4 v = w[i];
    s += (double)fabsf(v.x);
    s += (double)fabsf(v.y);
    s += (double)fabsf(v.z);
    s += (double)fabsf(v.w);
  }
  sm[threadIdx.x] = s;
  __syncthreads();
  for (int off = 128; off > 0; off >>= 1) {
    if (threadIdx.x < off) sm[threadIdx.x] += sm[threadIdx.x + off];
    __syncthreads();
  }
  if (threadIdx.x == 0) partial[blockIdx.x] = sm[0];
}

// ---------- pass 2: finalize abs_mean / thr for both weights ----------
__global__ void k_finalize(const double* __restrict__ partial,
                           float* __restrict__ scales, double inv_n) {
  __shared__ double sm[256];
  const int t = threadIdx.x;
  for (int seg = 0; seg < 2; ++seg) {
    const double* p = partial + seg * 1024;
    double s = p[t * 4] + p[t * 4 + 1] + p[t * 4 + 2] + p[t * 4 + 3];
    sm[t] = s;
    __syncthreads();
    for (int off = 128; off > 0; off >>= 1) {
      if (t < off) sm[t] += sm[t + off];
      __syncthreads();
    }
    if (t == 0) {
      float am = (float)(sm[0] * inv_n);
      am = fmaxf(am, 1e-5f);
      scales[seg * 2] = am;             // abs_mean
      scales[seg * 2 + 1] = 0.7f * am;  // threshold
    }
    __syncthreads();
  }
}

// ---------- ternarize: fp32 w -> bf16 q in {-1,0,+1} ----------
__global__ void k_ternarize(const float4* __restrict__ w, ushort4* __restrict__ q,
                            const float* __restrict__ scales, int sidx, int n4) {
  const float thr = scales[sidx * 2 + 1];
  const int stride = gridDim.x * blockDim.x;
  for (int i = blockIdx.x * blockDim.x + threadIdx.x; i < n4; i += stride) {
    float4 v = w[i];
    ushort4 o;
    o.x = v.x > thr ? 0x3F80u : (v.x < -thr ? 0xBF80u : 0u);
    o.y = v.y > thr ? 0x3F80u : (v.y < -thr ? 0xBF80u : 0u);
    o.z = v.z > thr ? 0x3F80u : (v.z < -thr ? 0xBF80u : 0u);
    o.w = v.w > thr ? 0x3F80u : (v.w < -thr ? 0xBF80u : 0u);
    q[i] = o;
  }
}

// ---------- x: fp32 -> bf16 ----------
__global__ void k_f32_to_bf16(const float4* __restrict__ x, ushort4* __restrict__ o,
                              int n4) {
  const int stride = gridDim.x * blockDim.x;
  for (int i = blockIdx.x * blockDim.x + threadIdx.x; i < n4; i += stride) {
    float4 v = x[i];
    ushort4 r;
    r.x = f2bf(v.x);
    r.y = f2bf(v.y);
    r.z = f2bf(v.z);
    r.w = f2bf(v.w);
    o[i] = r;
  }
}

// ============ 256x256 8-wave, BK=32, 2-buffer (2 blocks/CU) GEMM ============
// C = A * B^T. A[M][K], B[N][K] bf16; fp32 acc.
// Buffer i at elem offset i*BUFE: A[256][32] @ +0, B[256][32] @ +8192.
// Swizzle (4 chunks of 16B per 64B row): LDS[row][c] = G[row][c ^ ((row>>1)&3)];
// frag reads use chunk = kgrp ^ ((fr>>1)&3)  (8 bank-quads, 2-way free aliasing).
// Per tile: stage T+1 -> freed buffer (post-barrier safe); 12 ds_read_b128;
// 32 MFMA (2 setprio clusters); vmcnt(0); s_barrier.

// one global_load_lds: 1 KB = 16 rows x 64 B; wave-uniform r0
#define ST1(Gst, bufo, r0, k0)                        \
  gload_lds16(Gst + (size_t)(r0) * K + (k0),          \
              (void*)(lptr + (bufo) + (r0) * 32))

#define ST_A(bufo, k0) do { ST1(Ast, (bufo), w16, k0); ST1(Ast, (bufo), 128 + w16, k0); } while (0)
#define ST_B(bufo, k0) do { ST1(Bst, (bufo) + 8192, w16, k0); ST1(Bst, (bufo) + 8192, 128 + w16, k0); } while (0)

#define BAR()                           \
  do {                                  \
    asm volatile("" ::: "memory");      \
    __builtin_amdgcn_s_barrier();       \
    asm volatile("" ::: "memory");      \
  } while (0)

template <int EPI>
__global__ __launch_bounds__(512, 4) void k_gemm_bt(
    const unsigned short* __restrict__ A, const unsigned short* __restrict__ B,
    void* __restrict__ Cout, int M, int N, int K,
    const float* __restrict__ scales, int sidx, int nbx) {
  __shared__ __align__(16) unsigned short lds[2 * BUFE];  // 64 KiB
  unsigned short* lptr = lds;

  const int tid = threadIdx.x;
  const int lane = tid & 63;
  const int w = tid >> 6;   // wave 0..7
  const int wr = w >> 2;    // 0..1 -> 128 rows
  const int wc = w & 3;     // 0..3 -> 64 cols

  // T1: bijective XCD swizzle (gridDim.x % 8 == 0)
  const int nwg = gridDim.x;
  const int cpx = nwg >> 3;
  const int bid = blockIdx.x;
  const int swz = (bid & 7) * cpx + (bid >> 3);
  const int bm = swz / nbx;
  const int bn = swz % nbx;
  const int rowA0 = bm * BM;
  const int rowB0 = bn * BN;

  // staging lane geometry: 16 rows/instr; source col pre-swizzled (4-chunk dom)
  const int srow = lane >> 2;                              // 0..15
  const int scol = ((lane & 3) ^ ((lane >> 3) & 3)) << 3;  // elems
  const unsigned short* Ast = A + (size_t)(rowA0 + srow) * K + scol;
  const unsigned short* Bst = B + (size_t)(rowB0 + srow) * K + scol;

  // frag-read lane geometry: fr = row within 16-tile, kgrp = k-chunk
  const int fr = lane & 15;
  const int kgrp = lane >> 4;
  const int csw = ((kgrp ^ ((fr >> 1) & 3)) << 3);         // elems
  const int aoff = (wr * 128 + fr) * 32 + csw;
  const int boff = 8192 + (wc * 64 + fr) * 32 + csw;

  const int w16 = w << 4;

  f32x4 acc[8][4];
#pragma unroll
  for (int i = 0; i < 8; ++i)
#pragma unroll
    for (int j = 0; j < 4; ++j) acc[i][j] = (f32x4){0.f, 0.f, 0.f, 0.f};

  const int nk = K / BK;

  // prologue: stage T0 -> buf0; drain; barrier
  ST_A(0, 0);
  ST_B(0, 0);
  asm volatile("s_waitcnt vmcnt(0)" ::: "memory");
  BAR();

  for (int T = 0; T < nk; ++T) {
    const int cur = (T & 1) * BUFE;
    const int oth = BUFE - cur;

    // stage T+1 into the buffer freed at the last barrier; its loads fly
    // under this tile's reads+MFMA (~1240 cyc/SIMD > HBM latency)
    if (T + 1 < nk) {
      const int k1 = (T + 1) * BK;
      ST_A(oth, k1);
      ST_B(oth, k1);
    }

    // frag reads + MFMA; compiler schedules ds_reads/lgkmcnt/MFMA interleave
    short8 af[8], bq[4];
#pragma unroll
    for (int i = 0; i < 4; ++i)
      af[i] = *(const short8*)&lptr[cur + aoff + i * 512];
#pragma unroll
    for (int j = 0; j < 4; ++j)
      bq[j] = *(const short8*)&lptr[cur + boff + j * 512];

    __builtin_amdgcn_s_setprio(1);
#pragma unroll
    for (int i = 0; i < 4; ++i)
#pragma unroll
      for (int j = 0; j < 4; ++j)
        acc[i][j] = __builtin_amdgcn_mfma_f32_16x16x32_bf16(af[i], bq[j],
                                                            acc[i][j], 0, 0, 0);
    __builtin_amdgcn_s_setprio(0);

#pragma unroll
    for (int i = 4; i < 8; ++i)
      af[i] = *(const short8*)&lptr[cur + aoff + i * 512];

    __builtin_amdgcn_s_setprio(1);
#pragma unroll
    for (int i = 4; i < 8; ++i)
#pragma unroll
      for (int j = 0; j < 4; ++j)
        acc[i][j] = __builtin_amdgcn_mfma_f32_16x16x32_bf16(af[i], bq[j],
                                                            acc[i][j], 0, 0, 0);
    __builtin_amdgcn_s_setprio(0);

    // drain T+1's staging (only outstanding loads), then barrier:
    // all waves' staging visible + all reads of cur retired
    if (T + 1 < nk) {
      asm volatile("s_waitcnt vmcnt(0)" ::: "memory");
    }
    BAR();
  }

  // epilogue: C/D layout col = lane&15, row = (lane>>4)*4 + q
  const float s = scales[sidx * 2];
  const int crow0 = rowA0 + wr * 128 + (lane >> 4) * 4;
  const int ccol0 = rowB0 + wc * 64 + (lane & 15);
  if (EPI == 0) {
    const float s2 = s * s;
    unsigned short* C = (unsigned short*)Cout;
#pragma unroll
    for (int ri = 0; ri < 8; ++ri)
#pragma unroll
      for (int ci = 0; ci < 4; ++ci)
#pragma unroll
        for (int q = 0; q < 4; ++q) {
          float v = acc[ri][ci][q];
          v = fmaxf(v, 0.0f);
          v = v * v * s2;
          C[(size_t)(crow0 + ri * 16 + q) * N + (ccol0 + ci * 16)] = f2bf(v);
        }
  } else {
    float* C = (float*)Cout;
#pragma unroll
    for (int ri = 0; ri < 8; ++ri)
#pragma unroll
      for (int ci = 0; ci < 4; ++ci)
#pragma unroll
        for (int q = 0; q < 4; ++q)
          C[(size_t)(crow0 + ri * 16 + q) * N + (ccol0 + ci * 16)] =
              acc[ri][ci][q] * s;
  }
}

extern "C" void kernel_launch(void* const* d_in, const int* in_sizes, int n_in,
                              void* d_out, int out_size, void* d_ws, size_t ws_size,
                              hipStream_t stream) {
  const int Mdim = 32768;  // B*S
  const int Ddim = 2048;
  const int Hdim = 5120;
  const int NW = Hdim * Ddim;  // elements per weight

  const float* x = (const float*)d_in[0];
  const float* w_fc = (const float*)d_in[1];
  const float* w_proj = (const float*)d_in[2];
  float* out = (float*)d_out;

  char* ws = (char*)d_ws;
  double* partial = (double*)ws;                          // 16 KB
  float* scales = (float*)(ws + 16384);                   // 4 floats
  unsigned short* wq_fc = (unsigned short*)(ws + 32768);  // 20 MB
  unsigned short* wq_proj = wq_fc + (size_t)NW;           // 20 MB
  unsigned short* xbf = wq_proj + (size_t)NW;             // 128 MB
  unsigned short* hbf = xbf + (size_t)Mdim * Ddim;        // 320 MB

  // 1) abs-mean reductions (deterministic, fp64)
  k_reduce_abs<<<1024, 256, 0, stream>>>((const float4*)w_fc, NW / 4, partial);
  k_reduce_abs<<<1024, 256, 0, stream>>>((const float4*)w_proj, NW / 4,
                                         partial + 1024);
  k_finalize<<<1, 256, 0, stream>>>(partial, scales, 1.0 / (double)NW);

  // 2) ternarize weights -> bf16 q
  k_ternarize<<<2048, 256, 0, stream>>>((const float4*)w_fc, (ushort4*)wq_fc,
                                        scales, 0, NW / 4);
  k_ternarize<<<2048, 256, 0, stream>>>((const float4*)w_proj, (ushort4*)wq_proj,
                                        scales, 1, NW / 4);

  // 3) x -> bf16
  k_f32_to_bf16<<<2048, 256, 0, stream>>>((const float4*)x, (ushort4*)xbf,
                                          (Mdim * Ddim) / 4);

  // 4) h = relu(x @ Wfc^T * s)^2  [M x H] bf16
  k_gemm_bt<0><<<dim3((Hdim / BN) * (Mdim / BM)), 512, 0, stream>>>(
      xbf, wq_fc, hbf, Mdim, Hdim, Ddim, scales, 0, Hdim / BN);

  // 5) out = h @ Wproj^T * s  [M x D] fp32
  k_gemm_bt<1><<<dim3((Ddim / BN) * (Mdim / BM)), 512, 0, stream>>>(
      hbf, wq_proj, out, Mdim, Ddim, Hdim, scales, 1, Ddim / BN);
}

// Round 9
// 1452.956 us; speedup vs baseline: 8.8500x; 8.8500x over previous
//
#include <hip/hip_runtime.h>
#include <hip/hip_bf16.h>

// BitNet-style ternary MLP: out = relu(x @ Wfc_q^T * s_fc)^2 @ Wproj_q^T * s_proj
// B=8 S=4096 D=2048 H=5120 -> M=32768.
// GEMMs: 256x128 block tile, 8 waves of 64x64 (acc=64 VGPR -> fits the
// 128-VGPR/wave cap of 4 waves/SIMD), BK=32, 16x16x32 MFMA, THREE 24-KiB LDS
// buffers (72 KiB -> 2 blocks/CU). Inter-block asynchrony provides the
// MFMA/LDS overlap (independent barriers). Per tile: stage T+2 (3 gloads) into
// freed buffer, 8 ds_read_b128, 16 MFMA, counted vmcnt(3) gate, one s_barrier.
// T2 swizzle (4-chunk domain, proven 0-conflict) via pre-swizzled global src;
// T5 setprio; T1 bijective XCD swizzle.

typedef __attribute__((ext_vector_type(8))) short short8;
typedef __attribute__((ext_vector_type(4))) float f32x4;

#define BM 256
#define BN 128
#define BK 32
#define BUFE 12288  // elems: A[256][32] (8192) + B[128][32] (4096) = 24 KiB

__device__ __forceinline__ unsigned short f2bf(float f) {
  unsigned int u = __float_as_uint(f);
  u += 0x7FFFu + ((u >> 16) & 1u);  // RNE
  return (unsigned short)(u >> 16);
}

__device__ __forceinline__ void gload_lds16(const void* gsrc, void* ldst) {
  __builtin_amdgcn_global_load_lds(
      (const __attribute__((address_space(1))) unsigned int*)gsrc,
      (__attribute__((address_space(3))) unsigned int*)ldst, 16, 0, 0);
}

// ---------- pass 1: |w| sum partials (deterministic, fp64 accumulate) ----------
__global__ void k_reduce_abs(const float4* __restrict__ w, int n4,
                             double* __restrict__ partial) {
  __shared__ double sm[256];
  double s = 0.0;
  const int stride = gridDim.x * blockDim.x;
  for (int i = blockIdx.x * blockDim.x + threadIdx.x; i < n4; i += stride) {
    float4 v = w[i];
    s += (double)fabsf(v.x);
    s += (double)fabsf(v.y);
    s += (double)fabsf(v.z);
    s += (double)fabsf(v.w);
  }
  sm[threadIdx.x] = s;
  __syncthreads();
  for (int off = 128; off > 0; off >>= 1) {
    if (threadIdx.x < off) sm[threadIdx.x] += sm[threadIdx.x + off];
    __syncthreads();
  }
  if (threadIdx.x == 0) partial[blockIdx.x] = sm[0];
}

// ---------- pass 2: finalize abs_mean / thr for both weights ----------
__global__ void k_finalize(const double* __restrict__ partial,
                           float* __restrict__ scales, double inv_n) {
  __shared__ double sm[256];
  const int t = threadIdx.x;
  for (int seg = 0; seg < 2; ++seg) {
    const double* p = partial + seg * 1024;
    double s = p[t * 4] + p[t * 4 + 1] + p[t * 4 + 2] + p[t * 4 + 3];
    sm[t] = s;
    __syncthreads();
    for (int off = 128; off > 0; off >>= 1) {
      if (t < off) sm[t] += sm[t + off];
      __syncthreads();
    }
    if (t == 0) {
      float am = (float)(sm[0] * inv_n);
      am = fmaxf(am, 1e-5f);
      scales[seg * 2] = am;             // abs_mean
      scales[seg * 2 + 1] = 0.7f * am;  // threshold
    }
    __syncthreads();
  }
}

// ---------- ternarize: fp32 w -> bf16 q in {-1,0,+1} ----------
__global__ void k_ternarize(const float4* __restrict__ w, ushort4* __restrict__ q,
                            const float* __restrict__ scales, int sidx, int n4) {
  const float thr = scales[sidx * 2 + 1];
  const int stride = gridDim.x * blockDim.x;
  for (int i = blockIdx.x * blockDim.x + threadIdx.x; i < n4; i += stride) {
    float4 v = w[i];
    ushort4 o;
    o.x = v.x > thr ? 0x3F80u : (v.x < -thr ? 0xBF80u : 0u);
    o.y = v.y > thr ? 0x3F80u : (v.y < -thr ? 0xBF80u : 0u);
    o.z = v.z > thr ? 0x3F80u : (v.z < -thr ? 0xBF80u : 0u);
    o.w = v.w > thr ? 0x3F80u : (v.w < -thr ? 0xBF80u : 0u);
    q[i] = o;
  }
}

// ---------- x: fp32 -> bf16 ----------
__global__ void k_f32_to_bf16(const float4* __restrict__ x, ushort4* __restrict__ o,
                              int n4) {
  const int stride = gridDim.x * blockDim.x;
  for (int i = blockIdx.x * blockDim.x + threadIdx.x; i < n4; i += stride) {
    float4 v = x[i];
    ushort4 r;
    r.x = f2bf(v.x);
    r.y = f2bf(v.y);
    r.z = f2bf(v.z);
    r.w = f2bf(v.w);
    o[i] = r;
  }
}

// ====== 256x128 8-wave (64x64/wave), BK=32, 3-buffer, 2-blocks/CU GEMM ======
// C = A * B^T. A[M][K], B[N][K] bf16; fp32 acc.
// Buffer i at elem offset i*BUFE: A[256][32] @ +0, B[128][32] @ +8192.
// Swizzle (4 chunks of 16B per 64B row): LDS[row][c] = G[row][c ^ ((row>>1)&3)];
// frag reads use chunk = kgrp ^ ((fr>>1)&3)  (proven 0-conflict, r7).
// Staging: 24 x 1KB chunks, 3 per wave: A rows w*16, A rows 128+w*16, B rows w*16.
// Per tile: stage T+2 -> buffer freed by T-1; 8 ds_read_b128; 16 MFMA;
// vmcnt(3) gate; one s_barrier. Rotation cur<-nxt<-stg.

#define ST1(Gst, bufo, r0, k0)                        \
  gload_lds16(Gst + (size_t)(r0) * K + (k0),          \
              (void*)(lptr + (bufo) + (r0) * 32))

#define ST_TILE(bufo, k0)                      \
  do {                                         \
    ST1(Ast, (bufo), w16, k0);                 \
    ST1(Ast, (bufo), 128 + w16, k0);           \
    ST1(Bst, (bufo) + 8192, w16, k0);          \
  } while (0)

#define BAR()                           \
  do {                                  \
    asm volatile("" ::: "memory");      \
    __builtin_amdgcn_s_barrier();       \
    asm volatile("" ::: "memory");      \
  } while (0)

template <int EPI>
__global__ __launch_bounds__(512, 4) void k_gemm_bt(
    const unsigned short* __restrict__ A, const unsigned short* __restrict__ B,
    void* __restrict__ Cout, int M, int N, int K,
    const float* __restrict__ scales, int sidx, int nbx) {
  __shared__ __align__(16) unsigned short lds[3 * BUFE];  // 72 KiB
  unsigned short* lptr = lds;

  const int tid = threadIdx.x;
  const int lane = tid & 63;
  const int w = tid >> 6;   // wave 0..7
  const int wr = w >> 1;    // 0..3 -> 64-row block
  const int wc = w & 1;     // 0..1 -> 64-col block

  // T1: bijective XCD swizzle (gridDim.x % 8 == 0)
  const int nwg = gridDim.x;
  const int cpx = nwg >> 3;
  const int bid = blockIdx.x;
  const int swz = (bid & 7) * cpx + (bid >> 3);
  const int bm = swz / nbx;
  const int bn = swz % nbx;
  const int rowA0 = bm * BM;
  const int rowB0 = bn * BN;

  // staging lane geometry: 16 rows/instr; source col pre-swizzled (4-chunk dom)
  const int srow = lane >> 2;                              // 0..15
  const int scol = ((lane & 3) ^ ((lane >> 3) & 3)) << 3;  // elems
  const unsigned short* Ast = A + (size_t)(rowA0 + srow) * K + scol;
  const unsigned short* Bst = B + (size_t)(rowB0 + srow) * K + scol;

  // frag-read lane geometry: fr = row within 16-tile, kgrp = k-chunk
  const int fr = lane & 15;
  const int kgrp = lane >> 4;
  const int csw = ((kgrp ^ ((fr >> 1) & 3)) << 3);         // elems
  const int aoff = (wr * 64 + fr) * 32 + csw;
  const int boff = 8192 + (wc * 64 + fr) * 32 + csw;

  const int w16 = w << 4;

  f32x4 acc[4][4];
#pragma unroll
  for (int i = 0; i < 4; ++i)
#pragma unroll
    for (int j = 0; j < 4; ++j) acc[i][j] = (f32x4){0.f, 0.f, 0.f, 0.f};

  const int nk = K / BK;

  // prologue: stage T0 -> buf0, T1 -> buf1; wait T0; barrier
  ST_TILE(0, 0);
  if (nk > 1) {
    ST_TILE(BUFE, BK);
    asm volatile("s_waitcnt vmcnt(3)" ::: "memory");
  } else {
    asm volatile("s_waitcnt vmcnt(0)" ::: "memory");
  }
  BAR();

  int cur = 0, nxt = BUFE, stg = 2 * BUFE;
  for (int T = 0; T < nk; ++T) {
    // stage tile T+2 into the buffer freed by tile T-1 (readers retired
    // before the previous barrier)
    if (T + 2 < nk) ST_TILE(stg, (T + 2) * BK);

    // frag reads + MFMA; compiler schedules ds_reads/lgkmcnt/MFMA interleave
    short8 af[4], bq[4];
#pragma unroll
    for (int i = 0; i < 4; ++i)
      af[i] = *(const short8*)&lptr[cur + aoff + i * 512];
#pragma unroll
    for (int j = 0; j < 4; ++j)
      bq[j] = *(const short8*)&lptr[cur + boff + j * 512];

    __builtin_amdgcn_s_setprio(1);
#pragma unroll
    for (int i = 0; i < 4; ++i)
#pragma unroll
      for (int j = 0; j < 4; ++j)
        acc[i][j] = __builtin_amdgcn_mfma_f32_16x16x32_bf16(af[i], bq[j],
                                                            acc[i][j], 0, 0, 0);
    __builtin_amdgcn_s_setprio(0);

    // gate: tile T+1 must be fully staged; keep T+2's 3 loads in flight
    if (T + 1 < nk) {
      if (T + 2 < nk) {
        asm volatile("s_waitcnt vmcnt(3)" ::: "memory");
      } else {
        asm volatile("s_waitcnt vmcnt(0)" ::: "memory");
      }
    }
    BAR();  // nxt visible to all waves; cur's readers all retired

    const int t = cur;
    cur = nxt;
    nxt = stg;
    stg = t;
  }

  // epilogue: C/D layout col = lane&15, row = (lane>>4)*4 + q
  const float s = scales[sidx * 2];
  const int crow0 = rowA0 + wr * 64 + (lane >> 4) * 4;
  const int ccol0 = rowB0 + wc * 64 + (lane & 15);
  if (EPI == 0) {
    const float s2 = s * s;
    unsigned short* C = (unsigned short*)Cout;
#pragma unroll
    for (int ri = 0; ri < 4; ++ri)
#pragma unroll
      for (int ci = 0; ci < 4; ++ci)
#pragma unroll
        for (int q = 0; q < 4; ++q) {
          float v = acc[ri][ci][q];
          v = fmaxf(v, 0.0f);
          v = v * v * s2;
          C[(size_t)(crow0 + ri * 16 + q) * N + (ccol0 + ci * 16)] = f2bf(v);
        }
  } else {
    float* C = (float*)Cout;
#pragma unroll
    for (int ri = 0; ri < 4; ++ri)
#pragma unroll
      for (int ci = 0; ci < 4; ++ci)
#pragma unroll
        for (int q = 0; q < 4; ++q)
          C[(size_t)(crow0 + ri * 16 + q) * N + (ccol0 + ci * 16)] =
              acc[ri][ci][q] * s;
  }
}

extern "C" void kernel_launch(void* const* d_in, const int* in_sizes, int n_in,
                              void* d_out, int out_size, void* d_ws, size_t ws_size,
                              hipStream_t stream) {
  const int Mdim = 32768;  // B*S
  const int Ddim = 2048;
  const int Hdim = 5120;
  const int NW = Hdim * Ddim;  // elements per weight

  const float* x = (const float*)d_in[0];
  const float* w_fc = (const float*)d_in[1];
  const float* w_proj = (const float*)d_in[2];
  float* out = (float*)d_out;

  char* ws = (char*)d_ws;
  double* partial = (double*)ws;                          // 16 KB
  float* scales = (float*)(ws + 16384);                   // 4 floats
  unsigned short* wq_fc = (unsigned short*)(ws + 32768);  // 20 MB
  unsigned short* wq_proj = wq_fc + (size_t)NW;           // 20 MB
  unsigned short* xbf = wq_proj + (size_t)NW;             // 128 MB
  unsigned short* hbf = xbf + (size_t)Mdim * Ddim;        // 320 MB

  // 1) abs-mean reductions (deterministic, fp64)
  k_reduce_abs<<<1024, 256, 0, stream>>>((const float4*)w_fc, NW / 4, partial);
  k_reduce_abs<<<1024, 256, 0, stream>>>((const float4*)w_proj, NW / 4,
                                         partial + 1024);
  k_finalize<<<1, 256, 0, stream>>>(partial, scales, 1.0 / (double)NW);

  // 2) ternarize weights -> bf16 q
  k_ternarize<<<2048, 256, 0, stream>>>((const float4*)w_fc, (ushort4*)wq_fc,
                                        scales, 0, NW / 4);
  k_ternarize<<<2048, 256, 0, stream>>>((const float4*)w_proj, (ushort4*)wq_proj,
                                        scales, 1, NW / 4);

  // 3) x -> bf16
  k_f32_to_bf16<<<2048, 256, 0, stream>>>((const float4*)x, (ushort4*)xbf,
                                          (Mdim * Ddim) / 4);

  // 4) h = relu(x @ Wfc^T * s)^2  [M x H] bf16
  k_gemm_bt<0><<<dim3((Hdim / BN) * (Mdim / BM)), 512, 0, stream>>>(
      xbf, wq_fc, hbf, Mdim, Hdim, Ddim, scales, 0, Hdim / BN);

  // 5) out = h @ Wproj^T * s  [M x D] fp32
  k_gemm_bt<1><<<dim3((Ddim / BN) * (Mdim / BM)), 512, 0, stream>>>(
      hbf, wq_proj, out, Mdim, Ddim, Hdim, scales, 1, Ddim / BN);
}